// Round 7
// baseline (101.676 us; speedup 1.0000x reference)
//
#include <hip/hip_runtime.h>
#include <math.h>

#define NB 64
#define NL 512
#define ND 768

static constexpr float kCosEps = 1e-8f;
static constexpr double kBnEps = 1e-5;

// ---- workspace layout (bytes) ----
static constexpr size_t OFF_ACC = 0;                          // 2 doubles
static constexpr size_t OFF_CSN = 256;                        // [NB][ND] f32 colsum news (atomic)
static constexpr size_t SZ_CS   = (size_t)NB * ND * 4;        // 196608
static constexpr size_t OFF_CSP = OFF_CSN + SZ_CS;            // [NB][ND] f32 colsum post (atomic)
static constexpr size_t MEMSET_BYTES = OFF_CSP + SZ_CS;       // zero acc+csn+csp each call
static constexpr size_t OFF_COS = 393728;                     // [NB][NL] f32 cosine
static constexpr size_t SZ_BL   = (size_t)NB * NL * 4;
static constexpr size_t OFF_HI  = OFF_COS + SZ_BL;
static constexpr size_t OFF_HT  = OFF_HI + SZ_BL;
static constexpr size_t OFF_HB  = OFF_HT + SZ_BL;

__device__ __forceinline__ float dot4(float4 a, float4 b) {
    return a.x * b.x + a.y * b.y + a.z * b.z + a.w * b.w;
}

// ---------------------------------------------------------------------------
// k1 v7: register-stream k1 (r6 structure, 8 rows/wave).
// Six structural variants (r1-r6) all delivered 2.4-2.8 TB/s regardless of
// occupancy, load mechanism (VGPR vs global_load_lds), barriers, or data
// source (cold HBM vs warm L3 runs identical) -> per-XCD fabric-ingress
// throughput cap (~350 GB/s/XCD = 2.8 TB/s chip). 201 MB floor / 2.8 TB/s
// = 72 us. This version only amortizes the per-block reduce tail 2x.
// grid = NB*16 = 1024 blocks x 256 thr (4 waves), wave owns 8 rows.
// ---------------------------------------------------------------------------
__global__ __launch_bounds__(256) void k1_cos_colsum(
    const float* __restrict__ news, const float* __restrict__ post,
    float* __restrict__ cosv, float* __restrict__ csn,
    float* __restrict__ csp)
{
    __shared__ float red[8][ND];        // 24 KB reduce buffer
    const int b    = blockIdx.x >> 4;
    const int t    = blockIdx.x & 15;   // 32-row tile
    const int l0   = t * 32;
    const int tid  = threadIdx.x;
    const int wave = tid >> 6;          // 0..3
    const int lane = tid & 63;

    // wave owns rows l0 + wave*8 + {0..7}; row stride = 192 float4
    const size_t rbase = ((size_t)b * NL + l0 + wave * 8) * ND;
    const float4* nr = (const float4*)(news + rbase) + lane;
    const float4* pr = (const float4*)(post + rbase) + lane;

    float nn[8], pp[8], npd[8];
    float an[12], ap[12];
#pragma unroll
    for (int k = 0; k < 12; ++k) { an[k] = 0.f; ap[k] = 0.f; }

#pragma unroll
    for (int r = 0; r < 8; ++r) {
        const float4 N0 = nr[r * 192],      N1 = nr[r * 192 + 64],  N2 = nr[r * 192 + 128];
        const float4 P0 = pr[r * 192],      P1 = pr[r * 192 + 64],  P2 = pr[r * 192 + 128];
        nn[r]  = dot4(N0, N0) + dot4(N1, N1) + dot4(N2, N2);
        pp[r]  = dot4(P0, P0) + dot4(P1, P1) + dot4(P2, P2);
        npd[r] = dot4(N0, P0) + dot4(N1, P1) + dot4(N2, P2);
        an[0] += N0.x; an[1]  += N0.y; an[2]  += N0.z; an[3]  += N0.w;
        an[4] += N1.x; an[5]  += N1.y; an[6]  += N1.z; an[7]  += N1.w;
        an[8] += N2.x; an[9]  += N2.y; an[10] += N2.z; an[11] += N2.w;
        ap[0] += P0.x; ap[1]  += P0.y; ap[2]  += P0.z; ap[3]  += P0.w;
        ap[4] += P1.x; ap[5]  += P1.y; ap[6]  += P1.z; ap[7]  += P1.w;
        ap[8] += P2.x; ap[9]  += P2.y; ap[10] += P2.z; ap[11] += P2.w;
    }

    // ---- 24 independent shuffle-reduce chains, 6 stages ----
#pragma unroll
    for (int m = 1; m <= 32; m <<= 1) {
#pragma unroll
        for (int r = 0; r < 8; ++r) {
            nn[r]  += __shfl_xor(nn[r], m);
            pp[r]  += __shfl_xor(pp[r], m);
            npd[r] += __shfl_xor(npd[r], m);
        }
    }
    if (lane == 0) {
#pragma unroll
        for (int r = 0; r < 8; ++r) {
            const float dn = fmaxf(sqrtf(nn[r]), kCosEps) * fmaxf(sqrtf(pp[r]), kCosEps);
            cosv[b * NL + l0 + wave * 8 + r] = npd[r] / dn;
        }
    }

    // ---- colsum block-reduce + atomic accumulate ----
    {
        float4* wn = (float4*)&red[wave][0];
        float4* wp = (float4*)&red[4 + wave][0];
        wn[lane]       = make_float4(an[0], an[1], an[2], an[3]);
        wn[lane + 64]  = make_float4(an[4], an[5], an[6], an[7]);
        wn[lane + 128] = make_float4(an[8], an[9], an[10], an[11]);
        wp[lane]       = make_float4(ap[0], ap[1], ap[2], ap[3]);
        wp[lane + 64]  = make_float4(ap[4], ap[5], ap[6], ap[7]);
        wp[lane + 128] = make_float4(ap[8], ap[9], ap[10], ap[11]);
    }
    __syncthreads();
    for (int i = tid; i < ND; i += 256) {
        float sn = red[0][i] + red[1][i] + red[2][i] + red[3][i];
        float sp = red[4][i] + red[5][i] + red[6][i] + red[7][i];
        atomicAdd(&csn[b * ND + i], sn);
        atomicAdd(&csp[b * ND + i], sp);
    }
}

// ---------------------------------------------------------------------------
// k2: 3-tap horizontal conv of cos row (3 vertical-weight variants) +
// fp64 global sum / sum-of-squares with multiplicities (1, L-2, 1).
// ---------------------------------------------------------------------------
__global__ __launch_bounds__(256) void k2_conv_stats(
    const float* __restrict__ cosv, const float* __restrict__ g,
    float* __restrict__ hi, float* __restrict__ ht, float* __restrict__ hb,
    double* __restrict__ acc)
{
    __shared__ float row[NL + 2];
    __shared__ double sred[8];
    const int b   = blockIdx.x;
    const int tid = threadIdx.x;
    if (tid == 0) { row[0] = 0.f; row[NL + 1] = 0.f; }
    for (int j = tid; j < NL; j += 256) row[j + 1] = cosv[b * NL + j];
    __syncthreads();

    const float ci0 = g[0] + g[3] + g[6], ci1 = g[1] + g[4] + g[7], ci2 = g[2] + g[5] + g[8];
    const float ct0 = g[3] + g[6],        ct1 = g[4] + g[7],        ct2 = g[5] + g[8];
    const float cb0 = g[0] + g[3],        cb1 = g[1] + g[4],        cb2 = g[2] + g[5];

    double s = 0.0, s2 = 0.0;
    for (int j = tid; j < NL; j += 256) {
        const float a = row[j], c = row[j + 1], d = row[j + 2];
        const float vi = ci0 * a + ci1 * c + ci2 * d;
        const float vt = ct0 * a + ct1 * c + ct2 * d;
        const float vb = cb0 * a + cb1 * c + cb2 * d;
        hi[b * NL + j] = vi; ht[b * NL + j] = vt; hb[b * NL + j] = vb;
        s  += (double)vi * (NL - 2) + (double)vt + (double)vb;
        s2 += (double)vi * vi * (NL - 2) + (double)vt * vt + (double)vb * vb;
    }
    const int lane = tid & 63, wave = tid >> 6;
#pragma unroll
    for (int m = 32; m >= 1; m >>= 1) { s += __shfl_xor(s, m); s2 += __shfl_xor(s2, m); }
    if (lane == 0) { sred[wave] = s; sred[4 + wave] = s2; }
    __syncthreads();
    if (tid == 0) {
        atomicAdd(&acc[0], sred[0] + sred[1] + sred[2] + sred[3]);
        atomicAdd(&acc[1], sred[4] + sred[5] + sred[6] + sred[7]);
    }
}

// ---------------------------------------------------------------------------
// k3k4 fused: BN-normalize, z = h_hat @ W^T + b, collapsed softmax -> (a,ct,cb)
// in LDS, then the SAME block writes the 768 outputs for its batch b.
// abc never touches global memory; one launch instead of two.
// grid = NB blocks, 256 threads.
// ---------------------------------------------------------------------------
__global__ __launch_bounds__(256) void k3k4_linear_softmax_out(
    const float* __restrict__ hi, const float* __restrict__ ht,
    const float* __restrict__ hb, const float* __restrict__ W,
    const float* __restrict__ bias, const float* __restrict__ gamma,
    const float* __restrict__ beta, const double* __restrict__ acc,
    const float* __restrict__ csn, const float* __restrict__ csp,
    const float* __restrict__ news, const float* __restrict__ post,
    float* __restrict__ out)
{
    __shared__ float shi[NL], sht[NL], shb[NL];
    __shared__ float sred[12];
    __shared__ float abc3[3];
    const int b   = blockIdx.x;
    const int tid = threadIdx.x;

    const double N   = (double)NB * NL * NL;
    const double mu  = acc[0] / N;
    const double var = acc[1] / N - mu * mu;
    const float  sc  = gamma[0] * (float)(1.0 / sqrt(var + kBnEps));
    const float  sh  = beta[0] - (float)mu * sc;

    for (int j = tid; j < NL; j += 256) {
        shi[j] = hi[b * NL + j] * sc + sh;
        sht[j] = ht[b * NL + j] * sc + sh;
        shb[j] = hb[b * NL + j] * sc + sh;
    }
    __syncthreads();

    const float4* s4i = (const float4*)shi;
    const float4* s4t = (const float4*)sht;
    const float4* s4b = (const float4*)shb;

    float sa = 0.f, st = 0.f, sb = 0.f;
    for (int n = tid; n < NL; n += 256) {
        const float4* wr = (const float4*)(W + (size_t)n * NL);
        float zi = 0.f, zt = 0.f, zb = 0.f;
        for (int m = 0; m < NL / 4; ++m) {
            const float4 w  = wr[m];
            const float4 vi = s4i[m], vt = s4t[m], vb = s4b[m];
            zi += w.x * vi.x + w.y * vi.y + w.z * vi.z + w.w * vi.w;
            zt += w.x * vt.x + w.y * vt.y + w.z * vt.z + w.w * vt.w;
            zb += w.x * vb.x + w.y * vb.y + w.z * vb.z + w.w * vb.w;
        }
        const float bv = bias[n];
        zi += bv; zt += bv; zb += bv;
        const float M  = fmaxf(zi, fmaxf(zt, zb));
        const float ei = expf(zi - M), et = expf(zt - M), eb = expf(zb - M);
        const float r  = 1.f / ((float)(NL - 2) * ei + et + eb);
        sa += ei * r; st += et * r; sb += eb * r;
    }
    const int lane = tid & 63, wave = tid >> 6;
#pragma unroll
    for (int m = 32; m >= 1; m >>= 1) {
        sa += __shfl_xor(sa, m); st += __shfl_xor(st, m); sb += __shfl_xor(sb, m);
    }
    if (lane == 0) { sred[wave * 3] = sa; sred[wave * 3 + 1] = st; sred[wave * 3 + 2] = sb; }
    __syncthreads();
    if (tid == 0) {
        abc3[0] = sred[0] + sred[3] + sred[6] + sred[9];
        abc3[1] = sred[1] + sred[4] + sred[7] + sred[10];
        abc3[2] = sred[2] + sred[5] + sred[8] + sred[11];
    }
    __syncthreads();

    // ---- k4 part: outputs for batch b ----
    const float a  = abc3[0];
    const float ct = abc3[1];
    const float cb = abc3[2];
    const float invL = 1.f / NL;
    const size_t base = (size_t)b * NL * ND;
    for (int d = tid; d < ND; d += 256) {
        const float cn = csn[b * ND + d];
        const float cp = csp[b * ND + d];
        const float n0 = news[base + d], nL = news[base + (size_t)(NL - 1) * ND + d];
        const float p0 = post[base + d], pL = post[base + (size_t)(NL - 1) * ND + d];
        out[b * ND + d]           = (a * cn + (ct - a) * n0 + (cb - a) * nL) * invL;
        out[NB * ND + b * ND + d] = (a * cp + (ct - a) * p0 + (cb - a) * pL) * invL;
    }
}

extern "C" void kernel_launch(void* const* d_in, const int* in_sizes, int n_in,
                              void* d_out, int out_size, void* d_ws, size_t ws_size,
                              hipStream_t stream) {
    const float* news     = (const float*)d_in[0];
    const float* post     = (const float*)d_in[1];
    const float* g        = (const float*)d_in[2];
    const float* bn_gamma = (const float*)d_in[3];
    const float* bn_beta  = (const float*)d_in[4];
    const float* lin_w    = (const float*)d_in[5];
    const float* lin_b    = (const float*)d_in[6];
    float* out = (float*)d_out;
    char*  ws  = (char*)d_ws;

    double* acc = (double*)(ws + OFF_ACC);
    float* csn  = (float*)(ws + OFF_CSN);
    float* csp  = (float*)(ws + OFF_CSP);
    float* cosv = (float*)(ws + OFF_COS);
    float* hi   = (float*)(ws + OFF_HI);
    float* ht   = (float*)(ws + OFF_HT);
    float* hb   = (float*)(ws + OFF_HB);

    // zero acc + csn + csp (atomic accumulation targets) every call
    hipMemsetAsync(ws, 0, MEMSET_BYTES, stream);

    k1_cos_colsum<<<NB * 16, 256, 0, stream>>>(news, post, cosv, csn, csp);
    k2_conv_stats<<<NB, 256, 0, stream>>>(cosv, g, hi, ht, hb, acc);
    k3k4_linear_softmax_out<<<NB, 256, 0, stream>>>(hi, ht, hb, lin_w, lin_b,
                                                    bn_gamma, bn_beta, acc,
                                                    csn, csp, news, post, out);
}

// Round 8
// 95.347 us; speedup vs baseline: 1.0664x; 1.0664x over previous
//
#include <hip/hip_runtime.h>
#include <math.h>

#define NB 64
#define NL 512
#define ND 768

static constexpr float kCosEps = 1e-8f;
static constexpr double kBnEps = 1e-5;

// ---- workspace layout (bytes) ----
static constexpr size_t OFF_CSN = 0;                          // [NB][ND] f32 colsum news (atomic)
static constexpr size_t SZ_CS   = (size_t)NB * ND * 4;        // 196608
static constexpr size_t OFF_CSP = OFF_CSN + SZ_CS;            // [NB][ND] f32 colsum post (atomic)
static constexpr size_t MEMSET_BYTES = OFF_CSP + SZ_CS;       // zero csn+csp each call
static constexpr size_t OFF_COS = MEMSET_BYTES;               // [NB][NL] f32 cosine

__device__ __forceinline__ float dot4(float4 a, float4 b) {
    return a.x * b.x + a.y * b.y + a.z * b.z + a.w * b.w;
}

// ---------------------------------------------------------------------------
// k1: EXACT round-6 structure (the best measured: 73.3 +/- 0.2 us).
// Seven structural variants (r1-r7) all delivered 2.4-2.8 TB/s regardless of
// occupancy, load mechanism, barriers, or data source (cold HBM vs warm
// L3-resident replays identical) -> ~2.8 TB/s read-path cap for L2-miss
// traffic (~350 GB/s/XCD; matches m13 copy read component 395 GB/s/XCD).
// 201 MB mandatory read / 2.8 TB/s = ~72 us floor; this kernel is at it.
// grid = NB*32 = 2048 blocks x 256 thr (4 waves), wave owns 4 rows.
// ---------------------------------------------------------------------------
__global__ __launch_bounds__(256) void k1_cos_colsum(
    const float* __restrict__ news, const float* __restrict__ post,
    float* __restrict__ cosv, float* __restrict__ csn,
    float* __restrict__ csp)
{
    __shared__ float red[8][ND];        // 24 KB reduce buffer
    const int b    = blockIdx.x >> 5;
    const int t    = blockIdx.x & 31;   // 16-row tile
    const int l0   = t * 16;
    const int tid  = threadIdx.x;
    const int wave = tid >> 6;          // 0..3
    const int lane = tid & 63;

    // wave owns rows l0 + wave*4 + {0..3}; row stride = 192 float4
    const size_t rbase = ((size_t)b * NL + l0 + wave * 4) * ND;
    const float4* nr = (const float4*)(news + rbase) + lane;
    const float4* pr = (const float4*)(post + rbase) + lane;

    // ---- burst-load 24 float4 ----
    float4 N[4][3], P[4][3];
#pragma unroll
    for (int r = 0; r < 4; ++r)
#pragma unroll
        for (int k = 0; k < 3; ++k)
            N[r][k] = nr[r * 192 + k * 64];
#pragma unroll
    for (int r = 0; r < 4; ++r)
#pragma unroll
        for (int k = 0; k < 3; ++k)
            P[r][k] = pr[r * 192 + k * 64];

    // ---- per-row partials + colsum accumulators ----
    float nn[4], pp[4], npd[4];
    float an[12], ap[12];
#pragma unroll
    for (int k = 0; k < 12; ++k) { an[k] = 0.f; ap[k] = 0.f; }
#pragma unroll
    for (int r = 0; r < 4; ++r) {
        nn[r]  = dot4(N[r][0], N[r][0]) + dot4(N[r][1], N[r][1]) + dot4(N[r][2], N[r][2]);
        pp[r]  = dot4(P[r][0], P[r][0]) + dot4(P[r][1], P[r][1]) + dot4(P[r][2], P[r][2]);
        npd[r] = dot4(N[r][0], P[r][0]) + dot4(N[r][1], P[r][1]) + dot4(N[r][2], P[r][2]);
#pragma unroll
        for (int k = 0; k < 3; ++k) {
            an[4 * k + 0] += N[r][k].x; an[4 * k + 1] += N[r][k].y;
            an[4 * k + 2] += N[r][k].z; an[4 * k + 3] += N[r][k].w;
            ap[4 * k + 0] += P[r][k].x; ap[4 * k + 1] += P[r][k].y;
            ap[4 * k + 2] += P[r][k].z; ap[4 * k + 3] += P[r][k].w;
        }
    }

    // ---- 12 independent shuffle-reduce chains, 6 stages ----
#pragma unroll
    for (int m = 1; m <= 32; m <<= 1) {
#pragma unroll
        for (int r = 0; r < 4; ++r) {
            nn[r]  += __shfl_xor(nn[r], m);
            pp[r]  += __shfl_xor(pp[r], m);
            npd[r] += __shfl_xor(npd[r], m);
        }
    }
    if (lane == 0) {
#pragma unroll
        for (int r = 0; r < 4; ++r) {
            const float dn = fmaxf(sqrtf(nn[r]), kCosEps) * fmaxf(sqrtf(pp[r]), kCosEps);
            cosv[b * NL + l0 + wave * 4 + r] = npd[r] / dn;
        }
    }

    // ---- colsum block-reduce + atomic accumulate ----
    {
        float4* wn = (float4*)&red[wave][0];
        float4* wp = (float4*)&red[4 + wave][0];
        wn[lane]       = make_float4(an[0], an[1], an[2], an[3]);
        wn[lane + 64]  = make_float4(an[4], an[5], an[6], an[7]);
        wn[lane + 128] = make_float4(an[8], an[9], an[10], an[11]);
        wp[lane]       = make_float4(ap[0], ap[1], ap[2], ap[3]);
        wp[lane + 64]  = make_float4(ap[4], ap[5], ap[6], ap[7]);
        wp[lane + 128] = make_float4(ap[8], ap[9], ap[10], ap[11]);
    }
    __syncthreads();
    for (int i = tid; i < ND; i += 256) {
        float sn = red[0][i] + red[1][i] + red[2][i] + red[3][i];
        float sp = red[4][i] + red[5][i] + red[6][i] + red[7][i];
        atomicAdd(&csn[b * ND + i], sn);
        atomicAdd(&csp[b * ND + i], sp);
    }
}

// ---------------------------------------------------------------------------
// k234 fused: (k2) every block redundantly computes the GLOBAL BN stats from
// cosv (conv recomputed on the fly, fp64 accumulation, fixed order ->
// deterministic and identical across blocks); (k3) own batch's normalized
// conv rows + z = h @ W^T + b + collapsed softmax -> (a,ct,cb); (k4) outputs.
// Eliminates the hi/ht/hb global round-trip and two dispatches.
// grid = NB blocks, 256 threads.
// ---------------------------------------------------------------------------
__global__ __launch_bounds__(256) void k234_stats_linear_out(
    const float* __restrict__ cosv, const float* __restrict__ g,
    const float* __restrict__ W, const float* __restrict__ bias,
    const float* __restrict__ gamma, const float* __restrict__ beta,
    const float* __restrict__ csn, const float* __restrict__ csp,
    const float* __restrict__ news, const float* __restrict__ post,
    float* __restrict__ out)
{
    __shared__ float chunk[16][NL + 2];          // 32.9 KB padded rows
    __shared__ float shi[NL], sht[NL], shb[NL];  // 6 KB
    __shared__ double dred[8];
    __shared__ float sred[12];
    __shared__ float abc3[3];
    __shared__ float stats[2];                   // sc, sh
    const int b    = blockIdx.x;
    const int tid  = threadIdx.x;
    const int lane = tid & 63, wave = tid >> 6;

    // column sums of the 3x3 kernel for interior / top / bottom output rows
    const float ci0 = g[0] + g[3] + g[6], ci1 = g[1] + g[4] + g[7], ci2 = g[2] + g[5] + g[8];
    const float ct0 = g[3] + g[6],        ct1 = g[4] + g[7],        ct2 = g[5] + g[8];
    const float cb0 = g[0] + g[3],        cb1 = g[1] + g[4],        cb2 = g[2] + g[5];

    // ---- phase 1: global stats over all NB batches, multiplicities (1,L-2,1) ----
    double s = 0.0, s2 = 0.0;
    for (int c = 0; c < NB / 16; ++c) {
        for (int idx = tid; idx < 16 * NL; idx += 256) {
            const int bb = idx >> 9, j = idx & (NL - 1);
            chunk[bb][j + 1] = cosv[(c * 16 + bb) * NL + j];
        }
        if (tid < 16) { chunk[tid][0] = 0.f; chunk[tid][NL + 1] = 0.f; }
        __syncthreads();
        for (int idx = tid; idx < 16 * NL; idx += 256) {
            const int bb = idx >> 9, j = idx & (NL - 1);
            const float a = chunk[bb][j], cc = chunk[bb][j + 1], d = chunk[bb][j + 2];
            const float vi = ci0 * a + ci1 * cc + ci2 * d;
            const float vt = ct0 * a + ct1 * cc + ct2 * d;
            const float vb = cb0 * a + cb1 * cc + cb2 * d;
            s  += (double)vi * (NL - 2) + (double)vt + (double)vb;
            s2 += (double)vi * vi * (NL - 2) + (double)vt * vt + (double)vb * vb;
        }
        __syncthreads();
    }
#pragma unroll
    for (int m = 32; m >= 1; m >>= 1) { s += __shfl_xor(s, m); s2 += __shfl_xor(s2, m); }
    if (lane == 0) { dred[wave] = s; dred[4 + wave] = s2; }
    __syncthreads();
    if (tid == 0) {
        const double S  = dred[0] + dred[1] + dred[2] + dred[3];
        const double S2 = dred[4] + dred[5] + dred[6] + dred[7];
        const double N  = (double)NB * NL * NL;
        const double mu  = S / N;
        const double var = S2 / N - mu * mu;
        const float  sc  = gamma[0] * (float)(1.0 / sqrt(var + kBnEps));
        stats[0] = sc;
        stats[1] = beta[0] - (float)mu * sc;
    }
    __syncthreads();
    const float sc = stats[0], sh = stats[1];

    // ---- phase 2: own batch's normalized conv rows ----
    for (int j = tid; j < NL; j += 256) chunk[0][j + 1] = cosv[b * NL + j];
    if (tid == 0) { chunk[0][0] = 0.f; chunk[0][NL + 1] = 0.f; }
    __syncthreads();
    for (int j = tid; j < NL; j += 256) {
        const float a = chunk[0][j], cc = chunk[0][j + 1], d = chunk[0][j + 2];
        shi[j] = (ci0 * a + ci1 * cc + ci2 * d) * sc + sh;
        sht[j] = (ct0 * a + ct1 * cc + ct2 * d) * sc + sh;
        shb[j] = (cb0 * a + cb1 * cc + cb2 * d) * sc + sh;
    }
    __syncthreads();

    // ---- phase 3: z = shX @ W^T + b, collapsed softmax (mult 1, L-2, 1) ----
    const float4* s4i = (const float4*)shi;
    const float4* s4t = (const float4*)sht;
    const float4* s4b = (const float4*)shb;
    float sa = 0.f, st = 0.f, sb = 0.f;
    for (int n = tid; n < NL; n += 256) {
        const float4* wr = (const float4*)(W + (size_t)n * NL);
        float zi = 0.f, zt = 0.f, zb = 0.f;
        for (int m = 0; m < NL / 4; ++m) {
            const float4 w  = wr[m];
            const float4 vi = s4i[m], vt = s4t[m], vb = s4b[m];
            zi += w.x * vi.x + w.y * vi.y + w.z * vi.z + w.w * vi.w;
            zt += w.x * vt.x + w.y * vt.y + w.z * vt.z + w.w * vt.w;
            zb += w.x * vb.x + w.y * vb.y + w.z * vb.z + w.w * vb.w;
        }
        const float bv = bias[n];
        zi += bv; zt += bv; zb += bv;
        const float M  = fmaxf(zi, fmaxf(zt, zb));
        const float ei = expf(zi - M), et = expf(zt - M), eb = expf(zb - M);
        const float r  = 1.f / ((float)(NL - 2) * ei + et + eb);
        sa += ei * r; st += et * r; sb += eb * r;
    }
#pragma unroll
    for (int m = 32; m >= 1; m >>= 1) {
        sa += __shfl_xor(sa, m); st += __shfl_xor(st, m); sb += __shfl_xor(sb, m);
    }
    if (lane == 0) { sred[wave * 3] = sa; sred[wave * 3 + 1] = st; sred[wave * 3 + 2] = sb; }
    __syncthreads();
    if (tid == 0) {
        abc3[0] = sred[0] + sred[3] + sred[6] + sred[9];
        abc3[1] = sred[1] + sred[4] + sred[7] + sred[10];
        abc3[2] = sred[2] + sred[5] + sred[8] + sred[11];
    }
    __syncthreads();

    // ---- phase 4: outputs for batch b ----
    const float a  = abc3[0];
    const float ct = abc3[1];
    const float cb = abc3[2];
    const float invL = 1.f / NL;
    const size_t base = (size_t)b * NL * ND;
    for (int d = tid; d < ND; d += 256) {
        const float cn = csn[b * ND + d];
        const float cp = csp[b * ND + d];
        const float n0 = news[base + d], nL = news[base + (size_t)(NL - 1) * ND + d];
        const float p0 = post[base + d], pL = post[base + (size_t)(NL - 1) * ND + d];
        out[b * ND + d]           = (a * cn + (ct - a) * n0 + (cb - a) * nL) * invL;
        out[NB * ND + b * ND + d] = (a * cp + (ct - a) * p0 + (cb - a) * pL) * invL;
    }
}

extern "C" void kernel_launch(void* const* d_in, const int* in_sizes, int n_in,
                              void* d_out, int out_size, void* d_ws, size_t ws_size,
                              hipStream_t stream) {
    const float* news     = (const float*)d_in[0];
    const float* post     = (const float*)d_in[1];
    const float* g        = (const float*)d_in[2];
    const float* bn_gamma = (const float*)d_in[3];
    const float* bn_beta  = (const float*)d_in[4];
    const float* lin_w    = (const float*)d_in[5];
    const float* lin_b    = (const float*)d_in[6];
    float* out = (float*)d_out;
    char*  ws  = (char*)d_ws;

    float* csn  = (float*)(ws + OFF_CSN);
    float* csp  = (float*)(ws + OFF_CSP);
    float* cosv = (float*)(ws + OFF_COS);

    // zero csn + csp (atomic accumulation targets) every call
    hipMemsetAsync(ws, 0, MEMSET_BYTES, stream);

    k1_cos_colsum<<<NB * 32, 256, 0, stream>>>(news, post, cosv, csn, csp);
    k234_stats_linear_out<<<NB, 256, 0, stream>>>(cosv, g, lin_w, lin_b,
                                                  bn_gamma, bn_beta,
                                                  csn, csp, news, post, out);
}

// Round 9
// 87.905 us; speedup vs baseline: 1.1567x; 1.0847x over previous
//
#include <hip/hip_runtime.h>
#include <math.h>

#define NB 64
#define NL 512
#define ND 768

static constexpr float kCosEps = 1e-8f;
static constexpr double kBnEps = 1e-5;

// ---- workspace layout (bytes) ----
static constexpr size_t OFF_ACC = 0;                          // 2 doubles
static constexpr size_t OFF_CSN = 256;                        // [NB][ND] f32 colsum news (atomic)
static constexpr size_t SZ_CS   = (size_t)NB * ND * 4;        // 196608
static constexpr size_t OFF_CSP = OFF_CSN + SZ_CS;            // [NB][ND] f32 colsum post (atomic)
static constexpr size_t MEMSET_BYTES = OFF_CSP + SZ_CS;       // zero acc+csn+csp each call
static constexpr size_t OFF_COS = 393728;                     // [NB][NL] f32 cosine
static constexpr size_t SZ_BL   = (size_t)NB * NL * 4;
static constexpr size_t OFF_HI  = OFF_COS + SZ_BL;
static constexpr size_t OFF_HT  = OFF_HI + SZ_BL;
static constexpr size_t OFF_HB  = OFF_HT + SZ_BL;

__device__ __forceinline__ float dot4(float4 a, float4 b) {
    return a.x * b.x + a.y * b.y + a.z * b.z + a.w * b.w;
}

// ---------------------------------------------------------------------------
// k1: best-measured structure (r6/r8: 73.3-74.5 us, 2.77 TB/s delivered).
// Eight structural variants (r1-r8) all pinned at 2.4-2.8 TB/s regardless of
// occupancy, load mechanism (VGPR vs global_load_lds), barriers, and data
// source (cold HBM vs warm L3-resident replays identical) -> per-CU
// outstanding-miss-slot cap: ~32 lines x 128 B / ~900 cy x 2.4 GHz x 256 CU
// ~= 2.7 TB/s. 201 MB mandatory single-use read / 2.8 TB/s ~= 72 us floor.
// grid = NB*32 = 2048 blocks x 256 thr (4 waves), wave owns 4 rows.
// ---------------------------------------------------------------------------
__global__ __launch_bounds__(256) void k1_cos_colsum(
    const float* __restrict__ news, const float* __restrict__ post,
    float* __restrict__ cosv, float* __restrict__ csn,
    float* __restrict__ csp)
{
    __shared__ float red[8][ND];        // 24 KB reduce buffer
    const int b    = blockIdx.x >> 5;
    const int t    = blockIdx.x & 31;   // 16-row tile
    const int l0   = t * 16;
    const int tid  = threadIdx.x;
    const int wave = tid >> 6;          // 0..3
    const int lane = tid & 63;

    // wave owns rows l0 + wave*4 + {0..3}; row stride = 192 float4
    const size_t rbase = ((size_t)b * NL + l0 + wave * 4) * ND;
    const float4* nr = (const float4*)(news + rbase) + lane;
    const float4* pr = (const float4*)(post + rbase) + lane;

    // ---- burst-load 24 float4 ----
    float4 N[4][3], P[4][3];
#pragma unroll
    for (int r = 0; r < 4; ++r)
#pragma unroll
        for (int k = 0; k < 3; ++k)
            N[r][k] = nr[r * 192 + k * 64];
#pragma unroll
    for (int r = 0; r < 4; ++r)
#pragma unroll
        for (int k = 0; k < 3; ++k)
            P[r][k] = pr[r * 192 + k * 64];

    // ---- per-row partials + colsum accumulators ----
    float nn[4], pp[4], npd[4];
    float an[12], ap[12];
#pragma unroll
    for (int k = 0; k < 12; ++k) { an[k] = 0.f; ap[k] = 0.f; }
#pragma unroll
    for (int r = 0; r < 4; ++r) {
        nn[r]  = dot4(N[r][0], N[r][0]) + dot4(N[r][1], N[r][1]) + dot4(N[r][2], N[r][2]);
        pp[r]  = dot4(P[r][0], P[r][0]) + dot4(P[r][1], P[r][1]) + dot4(P[r][2], P[r][2]);
        npd[r] = dot4(N[r][0], P[r][0]) + dot4(N[r][1], P[r][1]) + dot4(N[r][2], P[r][2]);
#pragma unroll
        for (int k = 0; k < 3; ++k) {
            an[4 * k + 0] += N[r][k].x; an[4 * k + 1] += N[r][k].y;
            an[4 * k + 2] += N[r][k].z; an[4 * k + 3] += N[r][k].w;
            ap[4 * k + 0] += P[r][k].x; ap[4 * k + 1] += P[r][k].y;
            ap[4 * k + 2] += P[r][k].z; ap[4 * k + 3] += P[r][k].w;
        }
    }

    // ---- 12 independent shuffle-reduce chains, 6 stages ----
#pragma unroll
    for (int m = 1; m <= 32; m <<= 1) {
#pragma unroll
        for (int r = 0; r < 4; ++r) {
            nn[r]  += __shfl_xor(nn[r], m);
            pp[r]  += __shfl_xor(pp[r], m);
            npd[r] += __shfl_xor(npd[r], m);
        }
    }
    if (lane == 0) {
#pragma unroll
        for (int r = 0; r < 4; ++r) {
            const float dn = fmaxf(sqrtf(nn[r]), kCosEps) * fmaxf(sqrtf(pp[r]), kCosEps);
            cosv[b * NL + l0 + wave * 4 + r] = npd[r] / dn;
        }
    }

    // ---- colsum block-reduce + atomic accumulate ----
    {
        float4* wn = (float4*)&red[wave][0];
        float4* wp = (float4*)&red[4 + wave][0];
        wn[lane]       = make_float4(an[0], an[1], an[2], an[3]);
        wn[lane + 64]  = make_float4(an[4], an[5], an[6], an[7]);
        wn[lane + 128] = make_float4(an[8], an[9], an[10], an[11]);
        wp[lane]       = make_float4(ap[0], ap[1], ap[2], ap[3]);
        wp[lane + 64]  = make_float4(ap[4], ap[5], ap[6], ap[7]);
        wp[lane + 128] = make_float4(ap[8], ap[9], ap[10], ap[11]);
    }
    __syncthreads();
    for (int i = tid; i < ND; i += 256) {
        float sn = red[0][i] + red[1][i] + red[2][i] + red[3][i];
        float sp = red[4][i] + red[5][i] + red[6][i] + red[7][i];
        atomicAdd(&csn[b * ND + i], sn);
        atomicAdd(&csp[b * ND + i], sp);
    }
}

// ---------------------------------------------------------------------------
// k2: 3-tap horizontal conv of cos row (3 vertical-weight variants) +
// fp64 global sum / sum-of-squares with multiplicities (1, L-2, 1).
// ---------------------------------------------------------------------------
__global__ __launch_bounds__(256) void k2_conv_stats(
    const float* __restrict__ cosv, const float* __restrict__ g,
    float* __restrict__ hi, float* __restrict__ ht, float* __restrict__ hb,
    double* __restrict__ acc)
{
    __shared__ float row[NL + 2];
    __shared__ double sred[8];
    const int b   = blockIdx.x;
    const int tid = threadIdx.x;
    if (tid == 0) { row[0] = 0.f; row[NL + 1] = 0.f; }
    for (int j = tid; j < NL; j += 256) row[j + 1] = cosv[b * NL + j];
    __syncthreads();

    const float ci0 = g[0] + g[3] + g[6], ci1 = g[1] + g[4] + g[7], ci2 = g[2] + g[5] + g[8];
    const float ct0 = g[3] + g[6],        ct1 = g[4] + g[7],        ct2 = g[5] + g[8];
    const float cb0 = g[0] + g[3],        cb1 = g[1] + g[4],        cb2 = g[2] + g[5];

    double s = 0.0, s2 = 0.0;
    for (int j = tid; j < NL; j += 256) {
        const float a = row[j], c = row[j + 1], d = row[j + 2];
        const float vi = ci0 * a + ci1 * c + ci2 * d;
        const float vt = ct0 * a + ct1 * c + ct2 * d;
        const float vb = cb0 * a + cb1 * c + cb2 * d;
        hi[b * NL + j] = vi; ht[b * NL + j] = vt; hb[b * NL + j] = vb;
        s  += (double)vi * (NL - 2) + (double)vt + (double)vb;
        s2 += (double)vi * vi * (NL - 2) + (double)vt * vt + (double)vb * vb;
    }
    const int lane = tid & 63, wave = tid >> 6;
#pragma unroll
    for (int m = 32; m >= 1; m >>= 1) { s += __shfl_xor(s, m); s2 += __shfl_xor(s2, m); }
    if (lane == 0) { sred[wave] = s; sred[4 + wave] = s2; }
    __syncthreads();
    if (tid == 0) {
        atomicAdd(&acc[0], sred[0] + sred[1] + sred[2] + sred[3]);
        atomicAdd(&acc[1], sred[4] + sred[5] + sred[6] + sred[7]);
    }
}

// ---------------------------------------------------------------------------
// k3: normalize (global BN), z = h_hat @ W^T + b for the 3 variants,
// collapsed softmax over l (multiplicities 1, L-2, 1), sum over n.
// ---------------------------------------------------------------------------
__global__ __launch_bounds__(256) void k3_linear_softmax(
    const float* __restrict__ hi, const float* __restrict__ ht,
    const float* __restrict__ hb, const float* __restrict__ W,
    const float* __restrict__ bias, const float* __restrict__ gamma,
    const float* __restrict__ beta, const double* __restrict__ acc,
    float* __restrict__ abc)
{
    __shared__ float shi[NL], sht[NL], shb[NL];
    __shared__ float sred[12];
    const int b   = blockIdx.x;
    const int tid = threadIdx.x;

    const double N   = (double)NB * NL * NL;
    const double mu  = acc[0] / N;
    const double var = acc[1] / N - mu * mu;
    const float  sc  = gamma[0] * (float)(1.0 / sqrt(var + kBnEps));
    const float  sh  = beta[0] - (float)mu * sc;

    for (int j = tid; j < NL; j += 256) {
        shi[j] = hi[b * NL + j] * sc + sh;
        sht[j] = ht[b * NL + j] * sc + sh;
        shb[j] = hb[b * NL + j] * sc + sh;
    }
    __syncthreads();

    const float4* s4i = (const float4*)shi;
    const float4* s4t = (const float4*)sht;
    const float4* s4b = (const float4*)shb;

    float sa = 0.f, st = 0.f, sb = 0.f;
    for (int n = tid; n < NL; n += 256) {
        const float4* wr = (const float4*)(W + (size_t)n * NL);
        float zi = 0.f, zt = 0.f, zb = 0.f;
        for (int m = 0; m < NL / 4; ++m) {
            const float4 w  = wr[m];
            const float4 vi = s4i[m], vt = s4t[m], vb = s4b[m];
            zi += w.x * vi.x + w.y * vi.y + w.z * vi.z + w.w * vi.w;
            zt += w.x * vt.x + w.y * vt.y + w.z * vt.z + w.w * vt.w;
            zb += w.x * vb.x + w.y * vb.y + w.z * vb.z + w.w * vb.w;
        }
        const float bv = bias[n];
        zi += bv; zt += bv; zb += bv;
        const float M  = fmaxf(zi, fmaxf(zt, zb));
        const float ei = expf(zi - M), et = expf(zt - M), eb = expf(zb - M);
        const float r  = 1.f / ((float)(NL - 2) * ei + et + eb);
        sa += ei * r; st += et * r; sb += eb * r;
    }
    const int lane = tid & 63, wave = tid >> 6;
#pragma unroll
    for (int m = 32; m >= 1; m >>= 1) {
        sa += __shfl_xor(sa, m); st += __shfl_xor(st, m); sb += __shfl_xor(sb, m);
    }
    if (lane == 0) { sred[wave * 3] = sa; sred[wave * 3 + 1] = st; sred[wave * 3 + 2] = sb; }
    __syncthreads();
    if (tid == 0) {
        abc[b * 3 + 0] = sred[0] + sred[3] + sred[6] + sred[9];
        abc[b * 3 + 1] = sred[1] + sred[4] + sred[7] + sred[10];
        abc[b * 3 + 2] = sred[2] + sred[5] + sred[8] + sred[11];
    }
}

// ---------------------------------------------------------------------------
// k4: outputs. word_feat[b,d] = (a*colsum_n + (ct-a)*n0 + (cb-a)*nL)/L, same
// for post. grid = NB*ND/256 = 192.
// ---------------------------------------------------------------------------
__global__ __launch_bounds__(256) void k4_out(
    const float* __restrict__ news, const float* __restrict__ post,
    const float* __restrict__ csn, const float* __restrict__ csp,
    const float* __restrict__ abc, float* __restrict__ out)
{
    const int idx = blockIdx.x * 256 + threadIdx.x;
    if (idx >= NB * ND) return;
    const int b = idx / ND, d = idx - b * ND;
    const float a  = abc[b * 3 + 0];
    const float ct = abc[b * 3 + 1];
    const float cb = abc[b * 3 + 2];
    const float cn = csn[idx];
    const float cp = csp[idx];
    const size_t base = (size_t)b * NL * ND;
    const float n0 = news[base + d], nL = news[base + (size_t)(NL - 1) * ND + d];
    const float p0 = post[base + d], pL = post[base + (size_t)(NL - 1) * ND + d];
    const float invL = 1.f / NL;
    out[idx]           = (a * cn + (ct - a) * n0 + (cb - a) * nL) * invL;
    out[NB * ND + idx] = (a * cp + (ct - a) * p0 + (cb - a) * pL) * invL;
}

extern "C" void kernel_launch(void* const* d_in, const int* in_sizes, int n_in,
                              void* d_out, int out_size, void* d_ws, size_t ws_size,
                              hipStream_t stream) {
    const float* news     = (const float*)d_in[0];
    const float* post     = (const float*)d_in[1];
    const float* g        = (const float*)d_in[2];
    const float* bn_gamma = (const float*)d_in[3];
    const float* bn_beta  = (const float*)d_in[4];
    const float* lin_w    = (const float*)d_in[5];
    const float* lin_b    = (const float*)d_in[6];
    float* out = (float*)d_out;
    char*  ws  = (char*)d_ws;

    double* acc = (double*)(ws + OFF_ACC);
    float* csn  = (float*)(ws + OFF_CSN);
    float* csp  = (float*)(ws + OFF_CSP);
    float* cosv = (float*)(ws + OFF_COS);
    float* hi   = (float*)(ws + OFF_HI);
    float* ht   = (float*)(ws + OFF_HT);
    float* hb   = (float*)(ws + OFF_HB);
    float* abc  = (float*)(ws + OFF_HB + SZ_BL);

    // zero acc + csn + csp (atomic accumulation targets) every call
    hipMemsetAsync(ws, 0, MEMSET_BYTES, stream);

    k1_cos_colsum<<<NB * 32, 256, 0, stream>>>(news, post, cosv, csn, csp);
    k2_conv_stats<<<NB, 256, 0, stream>>>(cosv, g, hi, ht, hb, acc);
    k3_linear_softmax<<<NB, 256, 0, stream>>>(hi, ht, hb, lin_w, lin_b,
                                              bn_gamma, bn_beta, acc, abc);
    k4_out<<<192, 256, 0, stream>>>(news, post, csn, csp, abc, out);
}